// Round 6
// baseline (1405.241 us; speedup 1.0000x reference)
//
#include <hip/hip_runtime.h>
#include <hip/hip_bf16.h>

#define NDENSE 13
#define NSPARSE 26
#define NFEAT 39
#define EDIM 64
#define NLAYER 4
#define FFDIM 256
#define HIDN 256
#define VDN 50
#define VSN 50000
#define NSAMP 8192
#define MROWS 319488L     // NSAMP * NFEAT
#define LN_EPS 1e-5f

// Q pre-scale: HD^-0.5 * log2(e), so sigmoid = rcp(1 + exp2(-dot))
#define QSCL 0.5100697f
// gelu: x * sigmoid2(C1*x + C2*x^3), constants pre-multiplied by log2(e)
#define GC1 2.3022082f
#define GC2 0.10294324f

#define QST 20            // q/k/v row stride in f32 (80 B, 16B-aligned)
#define FST2 136          // ff scratch stride in bf16 (272 B)

// ---- packed (transposed, bf16) weights in d_ws after x ----
#define PK_WKT 4096           // wqT:  [64][64]
#define PK_WVT 8192
#define PK_WOT 12288
#define PK_W1T 16384          // w1T:  [256][64]
#define PK_W2T 32768          // w2T:  [64][256]
#define PK_LAYER 49152
#define PK_OW1T 196608        // ow1T: [256][2496]
#define PK_TOTAL 835584

typedef __bf16 bf16x8 __attribute__((ext_vector_type(8)));
typedef float f32x4 __attribute__((ext_vector_type(4)));

__device__ __forceinline__ f32x4 mfma16(bf16x8 a, bf16x8 b, f32x4 c) {
    return __builtin_amdgcn_mfma_f32_16x16x32_bf16(a, b, c, 0, 0, 0);
}

__device__ __forceinline__ float exp2_fast(float x) {
#if __has_builtin(__builtin_amdgcn_exp2f)
    return __builtin_amdgcn_exp2f(x);
#else
    return exp2f(x);
#endif
}

// x already scaled by log2(e)
__device__ __forceinline__ float sigmoid2(float x) {
    return __builtin_amdgcn_rcpf(1.0f + exp2_fast(-x));
}

__device__ __forceinline__ float gelu_f(float x) {
    return x * sigmoid2(GC1 * x + GC2 * x * x * x);
}

// B fragment from packed transposed weights: WT[col][k], k = k0..k0+7 contiguous.
__device__ __forceinline__ bf16x8 ldfrag(const __bf16* WT, int ld, int col, int k0) {
    return *(const bf16x8*)&WT[col * ld + k0];
}

// LayerNorm of one row (this lane's row) into K=64 A-fragment halves.
// Fragment layout: row = lane&15, k = (lane>>4)*8 + j
__device__ __forceinline__ void ln_frag(const __bf16* xr, const float* gam, const float* bet,
                                        int g, bf16x8& a0, bf16x8& a1) {
    bf16x8 v0 = *(const bf16x8*)(xr + g * 8);
    bf16x8 v1 = *(const bf16x8*)(xr + 32 + g * 8);
    float x0[8], x1[8], s = 0.f, ss = 0.f;
    #pragma unroll
    for (int j = 0; j < 8; ++j) {
        x0[j] = (float)v0[j]; x1[j] = (float)v1[j];
        s += x0[j] + x1[j];
        ss += x0[j] * x0[j] + x1[j] * x1[j];
    }
    s += __shfl_xor(s, 16); ss += __shfl_xor(ss, 16);
    s += __shfl_xor(s, 32); ss += __shfl_xor(ss, 32);
    float mn = s * (1.0f / 64.0f);
    float rs = rsqrtf(ss * (1.0f / 64.0f) - mn * mn + LN_EPS);
    float gv0[8], gv1[8], bv0[8], bv1[8];
    *(f32x4*)&gv0[0] = *(const f32x4*)&gam[g * 8];
    *(f32x4*)&gv0[4] = *(const f32x4*)&gam[g * 8 + 4];
    *(f32x4*)&gv1[0] = *(const f32x4*)&gam[32 + g * 8];
    *(f32x4*)&gv1[4] = *(const f32x4*)&gam[32 + g * 8 + 4];
    *(f32x4*)&bv0[0] = *(const f32x4*)&bet[g * 8];
    *(f32x4*)&bv0[4] = *(const f32x4*)&bet[g * 8 + 4];
    *(f32x4*)&bv1[0] = *(const f32x4*)&bet[32 + g * 8];
    *(f32x4*)&bv1[4] = *(const f32x4*)&bet[32 + g * 8 + 4];
    #pragma unroll
    for (int j = 0; j < 8; ++j) {
        a0[j] = (__bf16)((x0[j] - mn) * rs * gv0[j] + bv0[j]);
        a1[j] = (__bf16)((x1[j] - mn) * rs * gv1[j] + bv1[j]);
    }
}

// ---------------- weight pack: transpose + bf16 ----------------
__global__ __launch_bounds__(256)
void pack_weights(const float* __restrict__ wq, const float* __restrict__ wk,
                  const float* __restrict__ wv, const float* __restrict__ wo,
                  const float* __restrict__ w1, const float* __restrict__ w2,
                  const float* __restrict__ ow1, __bf16* __restrict__ pk)
{
    int idx = blockIdx.x * 256 + threadIdx.x;
    if (idx >= PK_TOTAL) return;
    float v;
    if (idx < PK_OW1T) {
        int l = idx / PK_LAYER, r = idx - l * PK_LAYER;
        const float* src; int sh, N, off;
        if (r < PK_WKT)      { src = wq + l * 4096;  sh = 6; N = 64;  off = r; }
        else if (r < PK_WVT) { src = wk + l * 4096;  sh = 6; N = 64;  off = r - PK_WKT; }
        else if (r < PK_WOT) { src = wv + l * 4096;  sh = 6; N = 64;  off = r - PK_WVT; }
        else if (r < PK_W1T) { src = wo + l * 4096;  sh = 6; N = 64;  off = r - PK_WOT; }
        else if (r < PK_W2T) { src = w1 + l * 16384; sh = 6; N = 256; off = r - PK_W1T; }
        else                 { src = w2 + l * 16384; sh = 8; N = 64;  off = r - PK_W2T; }
        int col = off >> sh, k = off & ((1 << sh) - 1);
        v = src[k * N + col];
    } else {
        int off = idx - PK_OW1T;
        int col = off / 2496, k = off - col * 2496;
        v = ow1[k * 256 + col];
    }
    pk[idx] = (__bf16)v;
}

// ---------------- embedding gather (x = [sample][39][64] bf16) ----------------
__global__ __launch_bounds__(256, 4)
void embed_gather(const int* __restrict__ dfeat, const int* __restrict__ sfeat,
                  const float* __restrict__ demb, const float* __restrict__ semb,
                  __bf16* __restrict__ x)
{
    long row = (long)blockIdx.x * 4 + (threadIdx.x >> 6);
    if (row >= MROWS) return;
    int lane = threadIdx.x & 63;
    int s = (int)(row / NFEAT), f = (int)(row - (long)s * NFEAT);
    float val;
    if (f < NDENSE) {
        int idx = dfeat[s * NDENSE + f];
        val = demb[(f * VDN + idx) * EDIM + lane];
    } else {
        int idx = sfeat[s * NSPARSE + (f - NDENSE)];
        val = semb[((long)(f - NDENSE) * VSN + idx) * EDIM + lane];
    }
    x[row * EDIM + lane] = (__bf16)val;
}

// global row for local row lr (0..79) of the 2-sample block at s0 (pad rows clamped)
__device__ __forceinline__ long grow_of(int s0, int lr) {
    int sm = (lr >= 40) ? 1 : 0;
    int f = lr - sm * 40;
    if (f > NFEAT - 1) f = NFEAT - 1;
    return (long)(s0 + sm) * NFEAT + f;
}

// ---------------- per-layer: LN1 + QKV + sigmoid-attn + O-proj + residual ----------------
__global__ __launch_bounds__(256, 4)
void attn_layer(const float* __restrict__ bq, const float* __restrict__ bk,
                const float* __restrict__ bv, const float* __restrict__ bo,
                const float* __restrict__ ln1g, const float* __restrict__ ln1b,
                const __bf16* __restrict__ pk, __bf16* __restrict__ x, int lay)
{
    __shared__ float qkv[3 * 80 * QST];   // 19200 B
    float* qbuf = qkv;
    float* kbuf = qkv + 80 * QST;
    float* vbuf = qkv + 2 * 80 * QST;

    const int tid = threadIdx.x, lane = tid & 63, wave = tid >> 6;
    const int g = lane >> 4, r16 = lane & 15;
    const int s0 = blockIdx.x * 2;

    const __bf16* wqT = pk + lay * PK_LAYER;
    const __bf16* wkT = wqT + PK_WKT;
    const __bf16* wvT = wqT + PK_WVT;
    const __bf16* woT = wqT + PK_WOT;
    const float* bq_l = bq + lay * EDIM;
    const float* bk_l = bk + lay * EDIM;
    const float* bv_l = bv + lay * EDIM;
    const float* bo_l = bo + lay * EDIM;
    const float* g1_l = ln1g + lay * EDIM;
    const float* be1_l = ln1b + lay * EDIM;

    // LN1 fragments: every wave owns tile `wave`; wave 0 also owns tile 4.
    bf16x8 lnA0[2], lnA4[2];
    ln_frag(&x[grow_of(s0, wave * 16 + r16) * EDIM], g1_l, be1_l, g, lnA0[0], lnA0[1]);
    if (wave == 0)
        ln_frag(&x[grow_of(s0, 64 + r16) * EDIM], g1_l, be1_l, g, lnA4[0], lnA4[1]);

    const int n_o = wave;              // this wave's 16-col O-proj strip
    f32x4 acc_o[5];
    {
        float bz = bo_l[n_o * 16 + r16];
        #pragma unroll
        for (int i = 0; i < 5; ++i) { f32x4 t = {bz, bz, bz, bz}; acc_o[i] = t; }
    }

    for (int qt = 0; qt < 4; ++qt) {   // quarter = 16 proj cols = 2 heads
        const int colq = qt * 16 + r16;

        // ---- A1: QKV projection for this quarter ----
        bf16x8 bfq0 = ldfrag(wqT, EDIM, colq, g * 8);
        bf16x8 bfq1 = ldfrag(wqT, EDIM, colq, 32 + g * 8);
        bf16x8 bfk0 = ldfrag(wkT, EDIM, colq, g * 8);
        bf16x8 bfk1 = ldfrag(wkT, EDIM, colq, 32 + g * 8);
        bf16x8 bfv0 = ldfrag(wvT, EDIM, colq, g * 8);
        bf16x8 bfv1 = ldfrag(wvT, EDIM, colq, 32 + g * 8);
        float biq = bq_l[colq], bik = bk_l[colq], biv = bv_l[colq];

        #pragma unroll
        for (int t = 0; t < 2; ++t) {
            if (t == 0 || wave == 0) {
                const int base = t ? 64 : wave * 16;
                f32x4 aq = {biq, biq, biq, biq};
                f32x4 ak = {bik, bik, bik, bik};
                f32x4 av = {biv, biv, biv, biv};
                if (t) {
                    aq = mfma16(lnA4[0], bfq0, aq); aq = mfma16(lnA4[1], bfq1, aq);
                    ak = mfma16(lnA4[0], bfk0, ak); ak = mfma16(lnA4[1], bfk1, ak);
                    av = mfma16(lnA4[0], bfv0, av); av = mfma16(lnA4[1], bfv1, av);
                } else {
                    aq = mfma16(lnA0[0], bfq0, aq); aq = mfma16(lnA0[1], bfq1, aq);
                    ak = mfma16(lnA0[0], bfk0, ak); ak = mfma16(lnA0[1], bfk1, ak);
                    av = mfma16(lnA0[0], bfv0, av); av = mfma16(lnA0[1], bfv1, av);
                }
                #pragma unroll
                for (int r = 0; r < 4; ++r) {
                    int row = base + g * 4 + r;
                    qbuf[row * QST + r16] = aq[r] * QSCL;   // pre-scaled for sigmoid
                    kbuf[row * QST + r16] = ak[r];
                    vbuf[row * QST + r16] = av[r];
                }
            }
        }
        __syncthreads();

        // ---- A2: sigmoid attention, 1 unit per wave (balanced), lane = q row ----
        {
            const int smp = wave >> 1, d0 = (wave & 1) * 8;
            int qq = lane < NFEAT ? lane : (NFEAT - 1);
            const float* Qr = &qbuf[(smp * 40 + qq) * QST + d0];
            f32x4 qv0 = *(const f32x4*)Qr;
            f32x4 qv1 = *(const f32x4*)(Qr + 4);
            f32x4 o0 = {0.f, 0.f, 0.f, 0.f}, o1 = {0.f, 0.f, 0.f, 0.f};
            for (int k = 0; k < NFEAT; ++k) {
                const float* Kr = &kbuf[(smp * 40 + k) * QST + d0];   // broadcast
                const float* Vr = &vbuf[(smp * 40 + k) * QST + d0];   // broadcast
                f32x4 kv0 = *(const f32x4*)Kr, kv1 = *(const f32x4*)(Kr + 4);
                f32x4 vv0 = *(const f32x4*)Vr, vv1 = *(const f32x4*)(Vr + 4);
                float dot = qv0[0]*kv0[0] + qv0[1]*kv0[1] + qv0[2]*kv0[2] + qv0[3]*kv0[3]
                          + qv1[0]*kv1[0] + qv1[1]*kv1[1] + qv1[2]*kv1[2] + qv1[3]*kv1[3];
                float sg = sigmoid2(dot);
                o0 += vv0 * sg;
                o1 += vv1 * sg;
            }
            if (lane < NFEAT) {      // o overwrites Q in place (own sample+cols only)
                float* Or = &qbuf[(smp * 40 + lane) * QST + d0];
                *(f32x4*)Or = o0;
                *(f32x4*)(Or + 4) = o1;
            }
        }
        __syncthreads();

        // ---- A3: O-proj partial for this quarter (K=16 zero-padded to 32) ----
        bf16x8 bfo;
        if (g < 2) {
            bfo = ldfrag(woT, EDIM, n_o * 16 + r16, qt * 16 + g * 8);
        } else {
            #pragma unroll
            for (int j = 0; j < 8; ++j) bfo[j] = (__bf16)0.0f;
        }
        #pragma unroll
        for (int mt = 0; mt < 5; ++mt) {
            bf16x8 af;
            if (g < 2) {
                const float* orow = &qbuf[(mt * 16 + r16) * QST + g * 8];
                f32x4 q0 = *(const f32x4*)orow;
                f32x4 q1 = *(const f32x4*)(orow + 4);
                #pragma unroll
                for (int j = 0; j < 4; ++j) { af[j] = (__bf16)q0[j]; af[4 + j] = (__bf16)q1[j]; }
            } else {
                #pragma unroll
                for (int j = 0; j < 8; ++j) af[j] = (__bf16)0.0f;
            }
            acc_o[mt] = mfma16(af, bfo, acc_o[mt]);
        }
        __syncthreads();   // next quarter overwrites q/k/v buffers
    }

    // ---- A4: residual add of O-projection -> global x ----
    #pragma unroll
    for (int mt = 0; mt < 5; ++mt) {
        #pragma unroll
        for (int r = 0; r < 4; ++r) {
            int lr = mt * 16 + g * 4 + r;
            int smp = (lr >= 40) ? 1 : 0;
            int f = lr - smp * 40;
            if (f < NFEAT) {
                long gr = ((long)(s0 + smp) * NFEAT + f) * EDIM + n_o * 16 + r16;
                x[gr] = (__bf16)((float)x[gr] + acc_o[mt][r]);
            }
        }
    }
}

// ---------------- per-layer: LN2 + MLP + residual (row-tiled, sample-agnostic) ----------------
__global__ __launch_bounds__(256, 6)
void mlp_layer(const float* __restrict__ ln2g, const float* __restrict__ ln2b,
               const float* __restrict__ b1, const float* __restrict__ b2,
               const __bf16* __restrict__ pk, __bf16* __restrict__ x, int lay)
{
    __shared__ __bf16 ffs_all[4][16 * FST2];   // 17408 B
    const int tid = threadIdx.x, lane = tid & 63, wave = tid >> 6;
    const int g = lane >> 4, r16 = lane & 15;

    const __bf16* w1T = pk + lay * PK_LAYER + PK_W1T;
    const __bf16* w2T = pk + lay * PK_LAYER + PK_W2T;
    const float* g2_l  = ln2g + lay * EDIM;
    const float* be2_l = ln2b + lay * EDIM;
    const float* b1_l  = b1 + lay * FFDIM;
    const float* b2_l  = b2 + lay * EDIM;

    const long r0 = (long)blockIdx.x * 64 + wave * 16;   // MROWS = 64*4992 exactly
    __bf16* ffs = ffs_all[wave];

    bf16x8 a0, a1;
    ln_frag(&x[(r0 + r16) * EDIM], g2_l, be2_l, g, a0, a1);

    f32x4 acc2[4];
    #pragma unroll
    for (int n2 = 0; n2 < 4; ++n2) {
        float bz = b2_l[n2 * 16 + r16];
        f32x4 t = {bz, bz, bz, bz};
        acc2[n2] = t;
    }
    #pragma unroll
    for (int p = 0; p < 2; ++p) {
        #pragma unroll
        for (int n = 0; n < 8; ++n) {
            int col = (p * 8 + n) * 16 + r16;
            float bz = b1_l[col];
            f32x4 acc = {bz, bz, bz, bz};
            acc = mfma16(a0, ldfrag(w1T, EDIM, col, g * 8), acc);
            acc = mfma16(a1, ldfrag(w1T, EDIM, col, 32 + g * 8), acc);
            #pragma unroll
            for (int r = 0; r < 4; ++r)
                ffs[(g * 4 + r) * FST2 + n * 16 + r16] = (__bf16)gelu_f(acc[r]);
        }
        #pragma unroll
        for (int n2 = 0; n2 < 4; ++n2) {
            #pragma unroll
            for (int kf = 0; kf < 4; ++kf) {
                bf16x8 af = *(const bf16x8*)&ffs[r16 * FST2 + kf * 32 + g * 8];
                acc2[n2] = mfma16(af,
                    ldfrag(w2T, FFDIM, n2 * 16 + r16, p * 128 + kf * 32 + g * 8),
                    acc2[n2]);
            }
        }
    }
    #pragma unroll
    for (int n2 = 0; n2 < 4; ++n2) {
        #pragma unroll
        for (int r = 0; r < 4; ++r) {
            long gr = (r0 + g * 4 + r) * EDIM + n2 * 16 + r16;
            x[gr] = (__bf16)((float)x[gr] + acc2[n2][r]);
        }
    }
}

// ---------------- head MLP ----------------
#define FFSTH 264
__global__ __launch_bounds__(512)
void final_mlp(const __bf16* __restrict__ flatX, const __bf16* __restrict__ ow1T,
               const float* __restrict__ ob1, const float* __restrict__ ow2,
               const float* __restrict__ ob2, float* __restrict__ out)
{
    __shared__ __bf16 hbuf[32 * FFSTH];   // 16896 B
    const int tid = threadIdx.x, lane = tid & 63, wave = tid >> 6;
    const int g = lane >> 4, r16 = lane & 15;
    const int m = wave & 1;              // m-tile 0/1 (16 samples each)
    const long base = (long)blockIdx.x * 32;
    const long arow = (base + m * 16 + r16) * (long)(NFEAT * EDIM);

    f32x4 acc[4];
    #pragma unroll
    for (int i = 0; i < 4; ++i) {
        int n = (wave >> 1) + i * 4;
        float bz = ob1[n * 16 + r16];
        f32x4 t = {bz, bz, bz, bz};
        acc[i] = t;
    }
    for (int kf = 0; kf < 78; ++kf) {    // K = 2496
        bf16x8 af = *(const bf16x8*)&flatX[arow + kf * 32 + g * 8];
        #pragma unroll
        for (int i = 0; i < 4; ++i) {
            int n = (wave >> 1) + i * 4;
            bf16x8 bfr = ldfrag(ow1T, NFEAT * EDIM, n * 16 + r16, kf * 32 + g * 8);
            acc[i] = mfma16(af, bfr, acc[i]);
        }
    }
    #pragma unroll
    for (int i = 0; i < 4; ++i) {
        int n = (wave >> 1) + i * 4;
        #pragma unroll
        for (int r = 0; r < 4; ++r) {
            float h = acc[i][r];
            hbuf[(m * 16 + g * 4 + r) * FFSTH + n * 16 + r16] = (__bf16)(h > 0.f ? h : 0.f);
        }
    }
    __syncthreads();
    float w2v0 = ow2[lane], w2v1 = ow2[64 + lane], w2v2 = ow2[128 + lane], w2v3 = ow2[192 + lane];
    float bias2 = ob2[0];
    #pragma unroll
    for (int i = 0; i < 4; ++i) {
        int sm = wave * 4 + i;
        float part = (float)hbuf[sm * FFSTH + lane]       * w2v0
                   + (float)hbuf[sm * FFSTH + 64 + lane]  * w2v1
                   + (float)hbuf[sm * FFSTH + 128 + lane] * w2v2
                   + (float)hbuf[sm * FFSTH + 192 + lane] * w2v3;
        #pragma unroll
        for (int off = 32; off >= 1; off >>= 1) part += __shfl_xor(part, off);
        if (lane == 0) {
            float z = part + bias2;
            out[base + sm] = __builtin_amdgcn_rcpf(1.0f + __expf(-z));
        }
    }
}

extern "C" void kernel_launch(void* const* d_in, const int* in_sizes, int n_in,
                              void* d_out, int out_size, void* d_ws, size_t ws_size,
                              hipStream_t stream)
{
    const int*   dfeat = (const int*)d_in[0];
    const int*   sfeat = (const int*)d_in[1];
    const float* demb  = (const float*)d_in[2];
    const float* semb  = (const float*)d_in[3];
    const float* wq    = (const float*)d_in[4];
    const float* bq    = (const float*)d_in[5];
    const float* wk    = (const float*)d_in[6];
    const float* bk    = (const float*)d_in[7];
    const float* wv    = (const float*)d_in[8];
    const float* bv    = (const float*)d_in[9];
    const float* wo    = (const float*)d_in[10];
    const float* bo    = (const float*)d_in[11];
    const float* ln1g  = (const float*)d_in[12];
    const float* ln1b  = (const float*)d_in[13];
    const float* ln2g  = (const float*)d_in[14];
    const float* ln2b  = (const float*)d_in[15];
    const float* w1    = (const float*)d_in[16];
    const float* b1    = (const float*)d_in[17];
    const float* w2    = (const float*)d_in[18];
    const float* b2    = (const float*)d_in[19];
    const float* ow1   = (const float*)d_in[20];
    const float* ob1   = (const float*)d_in[21];
    const float* ow2   = (const float*)d_in[22];
    const float* ob2   = (const float*)d_in[23];

    __bf16* x  = (__bf16*)d_ws;                      // 40.9 MB, [sample][39][64]
    __bf16* pk = ((__bf16*)d_ws) + (MROWS * EDIM);   // +1.7 MB packed weights
    float* out = (float*)d_out;

    pack_weights<<<(PK_TOTAL + 255) / 256, 256, 0, stream>>>(wq, wk, wv, wo, w1, w2, ow1, pk);
    embed_gather<<<(int)((MROWS + 3) / 4), 256, 0, stream>>>(dfeat, sfeat, demb, semb, x);
    for (int lay = 0; lay < NLAYER; ++lay) {
        attn_layer<<<NSAMP / 2, 256, 0, stream>>>(bq, bk, bv, bo, ln1g, ln1b, pk, x, lay);
        mlp_layer<<<(int)(MROWS / 64), 256, 0, stream>>>(ln2g, ln2b, b1, b2, pk, x, lay);
    }
    final_mlp<<<NSAMP / 32, 512, 0, stream>>>(x, pk + PK_OW1T, ob1, ow2, ob2, out);
}

// Round 7
// 806.249 us; speedup vs baseline: 1.7429x; 1.7429x over previous
//
#include <hip/hip_runtime.h>
#include <hip/hip_bf16.h>

#define NDENSE 13
#define NSPARSE 26
#define NFEAT 39
#define EDIM 64
#define NLAYER 4
#define FFDIM 256
#define VDN 50
#define VSN 50000
#define NSAMP 8192
#define LN_EPS 1e-5f

// Q pre-scale: HD^-0.5 * log2(e) so sigmoid = rcp(1+exp2(-dot))
#define QSCL 0.5100697f
// gelu: x * sigmoid2(C1*x + C2*x^3), constants pre-multiplied by log2(e)
#define GC1 2.3022082f
#define GC2 0.10294324f

#define XST 72     // xb row stride (bf16), 144 B
#define QST 72     // Qb/Kb row stride
#define VST 104    // Vt row stride (208 B, 16B-mult)
#define FST 264    // ff row stride (528 B, 16B-mult)

// LDS layout (bytes)
#define OFF_XB 0             // xb [80][72]  = 11520
#define OFF_QB 11520         // Qb [96][72]  = 13824 (also O after attention)
#define OFF_KB 25344         // Kb [96][72]  = 13824
#define OFF_VT 39168         // Vt [64][104] = 13312
#define SMEM_TOTAL 52480     // -> 3 blocks/CU
#define OFF_FF OFF_KB        // ff [48][264] = 25344, aliases Kb+Vt

// ---- packed (transposed, bf16) weights in d_ws after flatX ----
#define FLATX_ELEMS (8192L * NFEAT * EDIM)
#define PK_WKT 4096
#define PK_WVT 8192
#define PK_WOT 12288
#define PK_W1T 16384
#define PK_W2T 32768
#define PK_LAYER 49152
#define PK_OW1T 196608
#define PK_TOTAL 835584

typedef __bf16 bf16x8 __attribute__((ext_vector_type(8)));
typedef __bf16 bf16x4 __attribute__((ext_vector_type(4)));
typedef float f32x4 __attribute__((ext_vector_type(4)));
typedef int int32x4 __attribute__((ext_vector_type(4)));

__device__ __forceinline__ f32x4 mfma16(bf16x8 a, bf16x8 b, f32x4 c) {
    return __builtin_amdgcn_mfma_f32_16x16x32_bf16(a, b, c, 0, 0, 0);
}

__device__ __forceinline__ float exp2_fast(float x) {
#if __has_builtin(__builtin_amdgcn_exp2f)
    return __builtin_amdgcn_exp2f(x);
#else
    return exp2f(x);
#endif
}
__device__ __forceinline__ float sigmoid2(float x) {
    return __builtin_amdgcn_rcpf(1.0f + exp2_fast(-x));
}
__device__ __forceinline__ float gelu_f(float x) {
    return x * sigmoid2(GC1 * x + GC2 * x * x * x);
}

__device__ __forceinline__ bf16x8 ldfrag(const __bf16* WT, int ld, int col, int k0) {
    return *(const bf16x8*)&WT[col * ld + k0];
}
__device__ __forceinline__ bf16x4 pk4(f32x4 v) {
    bf16x4 r; r[0]=(__bf16)v[0]; r[1]=(__bf16)v[1]; r[2]=(__bf16)v[2]; r[3]=(__bf16)v[3]; return r;
}
__device__ __forceinline__ int pk2(float a, float b) {
    unsigned short ua = __builtin_bit_cast(unsigned short, (__bf16)a);
    unsigned short ub = __builtin_bit_cast(unsigned short, (__bf16)b);
    return (int)(((unsigned)ub << 16) | (unsigned)ua);
}
__device__ __forceinline__ void rmw4(__bf16* p, f32x4 a) {
    bf16x4 o = *(bf16x4*)p;
    f32x4 n = { (float)o[0]+a[0], (float)o[1]+a[1], (float)o[2]+a[2], (float)o[3]+a[3] };
    *(bf16x4*)p = pk4(n);
}
// packed xb row for attention-grid row q48 (48 rows/sample padded -> 40-row packed)
__device__ __forceinline__ int xrow(int q48) {
    int s = q48 >= 48 ? 1 : 0;
    int ql = q48 - 48 * s;
    if (ql > 39) ql = 39;
    return 40 * s + ql;
}

// LayerNorm of this lane's row into K=64 B-fragment halves (k = g*8+j / 32+g*8+j)
__device__ __forceinline__ void ln_frag(const __bf16* xr, const float* gam, const float* bet,
                                        int g, bf16x8& a0, bf16x8& a1) {
    bf16x8 v0 = *(const bf16x8*)(xr + g * 8);
    bf16x8 v1 = *(const bf16x8*)(xr + 32 + g * 8);
    float x0[8], x1[8], s = 0.f, ss = 0.f;
    #pragma unroll
    for (int j = 0; j < 8; ++j) {
        x0[j] = (float)v0[j]; x1[j] = (float)v1[j];
        s += x0[j] + x1[j];
        ss += x0[j] * x0[j] + x1[j] * x1[j];
    }
    s += __shfl_xor(s, 16); ss += __shfl_xor(ss, 16);
    s += __shfl_xor(s, 32); ss += __shfl_xor(ss, 32);
    float mn = s * (1.0f / 64.0f);
    float rs = rsqrtf(ss * (1.0f / 64.0f) - mn * mn + LN_EPS);
    float gv0[8], gv1[8], bv0[8], bv1[8];
    *(f32x4*)&gv0[0] = *(const f32x4*)&gam[g * 8];
    *(f32x4*)&gv0[4] = *(const f32x4*)&gam[g * 8 + 4];
    *(f32x4*)&gv1[0] = *(const f32x4*)&gam[32 + g * 8];
    *(f32x4*)&gv1[4] = *(const f32x4*)&gam[32 + g * 8 + 4];
    *(f32x4*)&bv0[0] = *(const f32x4*)&bet[g * 8];
    *(f32x4*)&bv0[4] = *(const f32x4*)&bet[g * 8 + 4];
    *(f32x4*)&bv1[0] = *(const f32x4*)&bet[32 + g * 8];
    *(f32x4*)&bv1[4] = *(const f32x4*)&bet[32 + g * 8 + 4];
    #pragma unroll
    for (int j = 0; j < 8; ++j) {
        a0[j] = (__bf16)((x0[j] - mn) * rs * gv0[j] + bv0[j]);
        a1[j] = (__bf16)((x1[j] - mn) * rs * gv1[j] + bv1[j]);
    }
}

// ---------------- weight pack: transpose + bf16 ----------------
__global__ __launch_bounds__(256)
void pack_weights(const float* __restrict__ wq, const float* __restrict__ wk,
                  const float* __restrict__ wv, const float* __restrict__ wo,
                  const float* __restrict__ w1, const float* __restrict__ w2,
                  const float* __restrict__ ow1, __bf16* __restrict__ pk)
{
    int idx = blockIdx.x * 256 + threadIdx.x;
    if (idx >= PK_TOTAL) return;
    float v;
    if (idx < PK_OW1T) {
        int l = idx / PK_LAYER, r = idx - l * PK_LAYER;
        const float* src; int sh, N, off;
        if (r < PK_WKT)      { src = wq + l * 4096;  sh = 6; N = 64;  off = r; }
        else if (r < PK_WVT) { src = wk + l * 4096;  sh = 6; N = 64;  off = r - PK_WKT; }
        else if (r < PK_WOT) { src = wv + l * 4096;  sh = 6; N = 64;  off = r - PK_WVT; }
        else if (r < PK_W1T) { src = wo + l * 4096;  sh = 6; N = 64;  off = r - PK_WOT; }
        else if (r < PK_W2T) { src = w1 + l * 16384; sh = 6; N = 256; off = r - PK_W1T; }
        else                 { src = w2 + l * 16384; sh = 8; N = 64;  off = r - PK_W2T; }
        int col = off >> sh, k = off & ((1 << sh) - 1);
        v = src[k * N + col];
    } else {
        int off = idx - PK_OW1T;
        int col = off / 2496, k = off - col * 2496;
        v = ow1[k * 256 + col];
    }
    pk[idx] = (__bf16)v;
}

// ---------------- fused 4-layer transformer, 2 samples / block ----------------
__global__ __launch_bounds__(256, 3)
void hstu_fused(const int* __restrict__ dfeat, const int* __restrict__ sfeat,
                const float* __restrict__ demb, const float* __restrict__ semb,
                const float* __restrict__ bq, const float* __restrict__ bk,
                const float* __restrict__ bv, const float* __restrict__ bo,
                const float* __restrict__ ln1g, const float* __restrict__ ln1b,
                const float* __restrict__ ln2g, const float* __restrict__ ln2b,
                const float* __restrict__ b1, const float* __restrict__ b2,
                const __bf16* __restrict__ pk, __bf16* __restrict__ flatX)
{
    __shared__ __align__(16) char smem[SMEM_TOTAL];
    __bf16* xb = (__bf16*)(smem + OFF_XB);
    __bf16* Qb = (__bf16*)(smem + OFF_QB);
    __bf16* Kb = (__bf16*)(smem + OFF_KB);
    __bf16* Vt = (__bf16*)(smem + OFF_VT);
    __bf16* ff = (__bf16*)(smem + OFF_FF);

    const int tid = threadIdx.x;
    const int lane = tid & 63, w = tid >> 6;
    const int g = lane >> 4, r16 = lane & 15;
    const int s0 = blockIdx.x * 2;

    // ---------------- embedding gather ----------------
    for (int r = w; r < 80; r += 4) {
        int sm = r / 40, f = r % 40;
        float val = 0.0f;
        if (f < NFEAT) {
            if (f < NDENSE) {
                int idx = dfeat[(s0 + sm) * NDENSE + f];
                val = demb[(f * VDN + idx) * EDIM + lane];
            } else {
                int idx = sfeat[(s0 + sm) * NSPARSE + (f - NDENSE)];
                val = semb[((long)(f - NDENSE) * VSN + idx) * EDIM + lane];
            }
        }
        xb[r * XST + lane] = (__bf16)val;
    }
    __syncthreads();

    for (int lay = 0; lay < NLAYER; ++lay) {
        const __bf16* wqT = pk + lay * PK_LAYER;
        const __bf16* wkT = wqT + PK_WKT;
        const __bf16* wvT = wqT + PK_WVT;
        const __bf16* woT = wqT + PK_WOT;
        const __bf16* w1T = wqT + PK_W1T;
        const __bf16* w2T = wqT + PK_W2T;
        const float* bq_l = bq + lay * EDIM;
        const float* bk_l = bk + lay * EDIM;
        const float* bv_l = bv + lay * EDIM;
        const float* bo_l = bo + lay * EDIM;
        const float* g1_l = ln1g + lay * EDIM;
        const float* be1_l = ln1b + lay * EDIM;
        const float* g2_l = ln2g + lay * EDIM;
        const float* be2_l = ln2b + lay * EDIM;
        const float* b1_l = b1 + lay * FFDIM;
        const float* b2_l = b2 + lay * EDIM;

        // ---- A1: QKV projection, swapped (C[outcol][q]); wave w -> outcol tile w ----
        {
            bf16x8 lnB[6][2];
            #pragma unroll
            for (int t = 0; t < 6; ++t)
                ln_frag(&xb[xrow(16 * t + r16) * XST], g1_l, be1_l, g, lnB[t][0], lnB[t][1]);

            const __bf16* Wm[3] = { wqT, wkT, wvT };
            const float*  Bm[3] = { bq_l, bk_l, bv_l };
            #pragma unroll
            for (int m = 0; m < 3; ++m) {
                bf16x8 A0 = ldfrag(Wm[m], EDIM, 16 * w + r16, 8 * g);
                bf16x8 A1 = ldfrag(Wm[m], EDIM, 16 * w + r16, 32 + 8 * g);
                f32x4 bi4 = *(const f32x4*)&Bm[m][16 * w + 4 * g];
                #pragma unroll
                for (int t = 0; t < 6; ++t) {
                    f32x4 acc = bi4;
                    acc = mfma16(A0, lnB[t][0], acc);
                    acc = mfma16(A1, lnB[t][1], acc);
                    int q48 = 16 * t + r16;
                    if (m == 0) {
                        f32x4 sc = { acc[0]*QSCL, acc[1]*QSCL, acc[2]*QSCL, acc[3]*QSCL };
                        *(bf16x4*)&Qb[q48 * QST + 16 * w + 4 * g] = pk4(sc);
                    } else if (m == 1) {
                        *(bf16x4*)&Kb[q48 * QST + 16 * w + 4 * g] = pk4(acc);
                    } else {
                        bool vz = ((t % 3) * 16 + r16) >= 39;   // zero pad kk cols
                        #pragma unroll
                        for (int r = 0; r < 4; ++r)
                            Vt[(16 * w + 4 * g + r) * VST + q48] =
                                vz ? (__bf16)0.0f : (__bf16)acc[r];
                    }
                }
            }
        }
        __syncthreads();   // B1: Q/K/Vt ready

        // ---- A2: attention; wave w owns heads 2w,2w+1 (d-cols 16w..16w+16) ----
        #pragma unroll
        for (int s = 0; s < 2; ++s) {
            // QK^T -> S^T[kk][q], sigmoid, pack bf16 pairs
            int sp[2][3][3][2];
            {
                bf16x8 qf[3], kf[3];
                #pragma unroll
                for (int hh = 0; hh < 2; ++hh) {
                    const int h = 2 * w + hh;
                    #pragma unroll
                    for (int t = 0; t < 3; ++t) {
                        bf16x8 z = {};
                        qf[t] = z; kf[t] = z;
                        if (g == 0) {
                            qf[t] = *(const bf16x8*)&Qb[(48*s + 16*t + r16) * QST + 8*h];
                            kf[t] = *(const bf16x8*)&Kb[(48*s + 16*t + r16) * QST + 8*h];
                        }
                    }
                    #pragma unroll
                    for (int kt = 0; kt < 3; ++kt) {
                        #pragma unroll
                        for (int qt = 0; qt < 3; ++qt) {
                            f32x4 acc = {0.f, 0.f, 0.f, 0.f};
                            acc = mfma16(kf[kt], qf[qt], acc);
                            sp[hh][kt][qt][0] = pk2(sigmoid2(acc[0]), sigmoid2(acc[1]));
                            sp[hh][kt][qt][1] = pk2(sigmoid2(acc[2]), sigmoid2(acc[3]));
                        }
                    }
                }
            }
            // PV: O^T[d][q] = Vt . P^T  (slots: head 2w kk0..47 | head 2w+1 kk0..47)
            f32x4 oacc[3];
            {
                f32x4 z = {0.f, 0.f, 0.f, 0.f};
                oacc[0] = z; oacc[1] = z; oacc[2] = z;
            }
            {
                const int sAh[3] = {0,0,1}, sAt[3] = {0,2,1};   // g<2 source (side,kt)
                const int sBh[3] = {0,1,1}, sBt[3] = {1,0,2};   // g>=2 source
                const int l0 = ((lane & 16) << 1) + r16;        // (g&1)*32 + r16
                const int l1 = l0 + 16;
                const bool selA = (g < 2);
                #pragma unroll
                for (int ks = 0; ks < 3; ++ks) {
                    int slot0 = 32 * ks + 8 * g;
                    int side = slot0 >= 48 ? 1 : 0;
                    int kk0 = slot0 - 48 * side;
                    bf16x8 av = {};
                    if (side == (r16 >> 3))
                        av = *(const bf16x8*)&Vt[(16 * w + r16) * VST + 48 * s + kk0];
                    #pragma unroll
                    for (int qt = 0; qt < 3; ++qt) {
                        int a0 = sp[sAh[ks]][sAt[ks]][qt][0];
                        int a1 = sp[sAh[ks]][sAt[ks]][qt][1];
                        int b0 = sp[sBh[ks]][sBt[ks]][qt][0];
                        int b1 = sp[sBh[ks]][sBt[ks]][qt][1];
                        int va0 = __shfl(a0, l0), va1 = __shfl(a1, l0);
                        int va2 = __shfl(a0, l1), va3 = __shfl(a1, l1);
                        int vb0 = __shfl(b0, l0), vb1 = __shfl(b1, l0);
                        int vb2 = __shfl(b0, l1), vb3 = __shfl(b1, l1);
                        int32x4 bi = { selA ? va0 : vb0, selA ? va1 : vb1,
                                       selA ? va2 : vb2, selA ? va3 : vb3 };
                        oacc[qt] = mfma16(av, __builtin_bit_cast(bf16x8, bi), oacc[qt]);
                    }
                }
            }
            // O overwrites Qb (exactly this wave's columns 16w..16w+16)
            #pragma unroll
            for (int qt = 0; qt < 3; ++qt) {
                int q48 = 48 * s + 16 * qt + r16;
                *(bf16x4*)&Qb[q48 * QST + 16 * w + 4 * g] = pk4(oacc[qt]);
            }
        }
        __syncthreads();   // B2: O complete

        // ---- A3: O-proj + residual; wave w -> outcol tile w ----
        {
            bf16x8 A0 = ldfrag(woT, EDIM, 16 * w + r16, 8 * g);
            bf16x8 A1 = ldfrag(woT, EDIM, 16 * w + r16, 32 + 8 * g);
            f32x4 bo4 = *(const f32x4*)&bo_l[16 * w + 4 * g];
            #pragma unroll
            for (int t = 0; t < 6; ++t) {
                bf16x8 B0 = *(const bf16x8*)&Qb[(16 * t + r16) * QST + 8 * g];
                bf16x8 B1 = *(const bf16x8*)&Qb[(16 * t + r16) * QST + 32 + 8 * g];
                f32x4 acc = bo4;
                acc = mfma16(A0, B0, acc);
                acc = mfma16(A1, B1, acc);
                int ql = (t % 3) * 16 + r16;
                if (ql <= 39)
                    rmw4(&xb[(40 * (t / 3) + ql) * XST + 16 * w + 4 * g], acc);
            }
        }
        __syncthreads();   // B3: xb updated; Kb/Vt free for ff

        // ---- A4: MLP, one pass per sample (q-tiles 3p..3p+3) ----
        #pragma unroll
        for (int p = 0; p < 2; ++p) {
            bf16x8 ln2B[3][2];
            #pragma unroll
            for (int tt = 0; tt < 3; ++tt)
                ln_frag(&xb[xrow(48 * p + 16 * tt + r16) * XST], g2_l, be2_l, g,
                        ln2B[tt][0], ln2B[tt][1]);
            // up: wave w -> ffcol tiles 4w..4w+4
            #pragma unroll
            for (int ft = 0; ft < 4; ++ft) {
                int m = 4 * w + ft;
                bf16x8 A0 = ldfrag(w1T, EDIM, 16 * m + r16, 8 * g);
                bf16x8 A1 = ldfrag(w1T, EDIM, 16 * m + r16, 32 + 8 * g);
                f32x4 b14 = *(const f32x4*)&b1_l[16 * m + 4 * g];
                #pragma unroll
                for (int tt = 0; tt < 3; ++tt) {
                    f32x4 acc = b14;
                    acc = mfma16(A0, ln2B[tt][0], acc);
                    acc = mfma16(A1, ln2B[tt][1], acc);
                    f32x4 gl = { gelu_f(acc[0]), gelu_f(acc[1]),
                                 gelu_f(acc[2]), gelu_f(acc[3]) };
                    *(bf16x4*)&ff[(16 * tt + r16) * FST + 16 * m + 4 * g] = pk4(gl);
                }
            }
            __syncthreads();
            // down: wave w -> outcol tile w
            {
                f32x4 b24 = *(const f32x4*)&b2_l[16 * w + 4 * g];
                #pragma unroll
                for (int tt = 0; tt < 3; ++tt) {
                    f32x4 acc = b24;
                    #pragma unroll
                    for (int kf = 0; kf < 8; ++kf) {
                        bf16x8 Af = ldfrag(w2T, FFDIM, 16 * w + r16, 32 * kf + 8 * g);
                        bf16x8 Bf = *(const bf16x8*)&ff[(16 * tt + r16) * FST + 32 * kf + 8 * g];
                        acc = mfma16(Af, Bf, acc);
                    }
                    int ql = 16 * tt + r16;
                    if (ql <= 39)
                        rmw4(&xb[(40 * p + ql) * XST + 16 * w + 4 * g], acc);
                }
            }
            __syncthreads();
        }
    }

    // ---------------- write flat activations ----------------
    for (int r = w; r < 80; r += 4) {
        int sm = r / 40, f = r % 40;
        if (f < NFEAT)
            flatX[((long)(s0 + sm) * NFEAT + f) * EDIM + lane] = xb[r * XST + lane];
    }
}

// ---------------- head MLP ----------------
#define FFSTH 264
__global__ __launch_bounds__(512)
void final_mlp(const __bf16* __restrict__ flatX, const __bf16* __restrict__ ow1T,
               const float* __restrict__ ob1, const float* __restrict__ ow2,
               const float* __restrict__ ob2, float* __restrict__ out)
{
    __shared__ __bf16 hbuf[32 * FFSTH];
    const int tid = threadIdx.x, lane = tid & 63, wave = tid >> 6;
    const int g = lane >> 4, r16 = lane & 15;
    const int m = wave & 1;
    const long base = (long)blockIdx.x * 32;
    const long arow = (base + m * 16 + r16) * (long)(NFEAT * EDIM);

    f32x4 acc[4];
    #pragma unroll
    for (int i = 0; i < 4; ++i) {
        int n = (wave >> 1) + i * 4;
        float bz = ob1[n * 16 + r16];
        f32x4 t = {bz, bz, bz, bz};
        acc[i] = t;
    }
    for (int kf = 0; kf < 78; ++kf) {
        bf16x8 af = *(const bf16x8*)&flatX[arow + kf * 32 + g * 8];
        #pragma unroll
        for (int i = 0; i < 4; ++i) {
            int n = (wave >> 1) + i * 4;
            bf16x8 bfr = ldfrag(ow1T, NFEAT * EDIM, n * 16 + r16, kf * 32 + g * 8);
            acc[i] = mfma16(af, bfr, acc[i]);
        }
    }
    #pragma unroll
    for (int i = 0; i < 4; ++i) {
        int n = (wave >> 1) + i * 4;
        #pragma unroll
        for (int r = 0; r < 4; ++r) {
            float h = acc[i][r];
            hbuf[(m * 16 + g * 4 + r) * FFSTH + n * 16 + r16] = (__bf16)(h > 0.f ? h : 0.f);
        }
    }
    __syncthreads();
    float w2v0 = ow2[lane], w2v1 = ow2[64 + lane], w2v2 = ow2[128 + lane], w2v3 = ow2[192 + lane];
    float bias2 = ob2[0];
    #pragma unroll
    for (int i = 0; i < 4; ++i) {
        int sm = wave * 4 + i;
        float part = (float)hbuf[sm * FFSTH + lane]       * w2v0
                   + (float)hbuf[sm * FFSTH + 64 + lane]  * w2v1
                   + (float)hbuf[sm * FFSTH + 128 + lane] * w2v2
                   + (float)hbuf[sm * FFSTH + 192 + lane] * w2v3;
        #pragma unroll
        for (int off = 32; off >= 1; off >>= 1) part += __shfl_xor(part, off);
        if (lane == 0) {
            float z = part + bias2;
            out[base + sm] = __builtin_amdgcn_rcpf(1.0f + __expf(-z));
        }
    }
}

extern "C" void kernel_launch(void* const* d_in, const int* in_sizes, int n_in,
                              void* d_out, int out_size, void* d_ws, size_t ws_size,
                              hipStream_t stream)
{
    const int*   dfeat = (const int*)d_in[0];
    const int*   sfeat = (const int*)d_in[1];
    const float* demb  = (const float*)d_in[2];
    const float* semb  = (const float*)d_in[3];
    const float* wq    = (const float*)d_in[4];
    const float* bq    = (const float*)d_in[5];
    const float* wk    = (const float*)d_in[6];
    const float* bk    = (const float*)d_in[7];
    const float* wv    = (const float*)d_in[8];
    const float* bv    = (const float*)d_in[9];
    const float* wo    = (const float*)d_in[10];
    const float* bo    = (const float*)d_in[11];
    const float* ln1g  = (const float*)d_in[12];
    const float* ln1b  = (const float*)d_in[13];
    const float* ln2g  = (const float*)d_in[14];
    const float* ln2b  = (const float*)d_in[15];
    const float* w1    = (const float*)d_in[16];
    const float* b1    = (const float*)d_in[17];
    const float* w2    = (const float*)d_in[18];
    const float* b2    = (const float*)d_in[19];
    const float* ow1   = (const float*)d_in[20];
    const float* ob1   = (const float*)d_in[21];
    const float* ow2   = (const float*)d_in[22];
    const float* ob2   = (const float*)d_in[23];

    __bf16* flatX = (__bf16*)d_ws;
    __bf16* pk    = ((__bf16*)d_ws) + FLATX_ELEMS;
    float* out = (float*)d_out;

    pack_weights<<<(PK_TOTAL + 255) / 256, 256, 0, stream>>>(wq, wk, wv, wo, w1, w2, ow1, pk);
    hstu_fused<<<NSAMP / 2, 256, 0, stream>>>(dfeat, sfeat, demb, semb,
        bq, bk, bv, bo, ln1g, ln1b, ln2g, ln2b, b1, b2, pk, flatX);
    final_mlp<<<NSAMP / 32, 512, 0, stream>>>(flatX, pk + PK_OW1T, ob1, ow2, ob2, out);
}